// Round 14
// baseline (477.186 us; speedup 1.0000x reference)
//
#include <hip/hip_runtime.h>
#include <math.h>

// Problem constants (match reference)
#define NB   64     // num_groups (B)
#define NG   32     // group_size (G)
#define ND   2000   // output dim D
#define NM   16     // m_samples
#define NE   16     // noise dim
#define NDIN 256
#define NK   272    // DIN + E

__device__ __forceinline__ float clampf(float v, float lo, float hi) {
    return fminf(fmaxf(v, lo), hi);
}

__device__ __forceinline__ float softplusf(float v) {
    return (v > 20.f) ? v : log1pf(expf(v));
}

// Broadcast lane `lane`'s value wave-uniformly (lives in SGPR).
__device__ __forceinline__ float readlane_f(float v, int lane) {
    return __int_as_float(__builtin_amdgcn_readlane(__float_as_int(v), lane));
}

// Fully-packed butterfly: reduce v[0..31] across 64 lanes in 32 shuffles.
// Returns the wave total for g = (lane>>1)&31 (dup on lane pairs).
// HW-verified rounds 3-13.
__device__ __forceinline__ float wave_sum32(float v[NG], int lane) {
    {   const bool hi = (lane & 32) != 0;
        #pragma unroll
        for (int k = 0; k < 16; ++k) {
            float s = hi ? v[k] : v[k + 16];
            float r = __shfl_xor(s, 32);
            v[k] = (hi ? v[k + 16] : v[k]) + r;
        }
    }
    {   const bool hi = (lane & 16) != 0;
        #pragma unroll
        for (int k = 0; k < 8; ++k) {
            float s = hi ? v[k] : v[k + 8];
            float r = __shfl_xor(s, 16);
            v[k] = (hi ? v[k + 8] : v[k]) + r;
        }
    }
    {   const bool hi = (lane & 8) != 0;
        #pragma unroll
        for (int k = 0; k < 4; ++k) {
            float s = hi ? v[k] : v[k + 4];
            float r = __shfl_xor(s, 8);
            v[k] = (hi ? v[k + 4] : v[k]) + r;
        }
    }
    {   const bool hi = (lane & 4) != 0;
        #pragma unroll
        for (int k = 0; k < 2; ++k) {
            float s = hi ? v[k] : v[k + 2];
            float r = __shfl_xor(s, 4);
            v[k] = (hi ? v[k + 2] : v[k]) + r;
        }
    }
    {   const bool hi = (lane & 2) != 0;
        float s = hi ? v[0] : v[1];
        float r = __shfl_xor(s, 2);
        v[0] = (hi ? v[1] : v[0]) + r;
    }
    v[0] += __shfl_xor(v[0], 1);
    return v[0];
}

// ---------------------------------------------------------------------------
// Kernel A: 512 blocks x 512 threads.  Block q -> (cx = q&7, b = q>>3).
// Phase 1 (xpred): ZERO-LDS GEMM.  x-row values are wave-uniform (rows
//   assigned per wave) -> scalar SGPR loads on the SMEM pipe; W float2 in
//   VGPRs from L2.  Round-13 lesson: every LDS-staged xpred variant was
//   DS-pipe-bound (~12 cyc/b128 on the one per-CU LDS pipe, 16 waves deep)
//   — that was the invariant ~120-155 us.  Wave (rh,dh): rows rh*8..rh*8+8,
//   d-half dh*128 within window p*256 (p = q&7; last window 208 wide).
// Phase 2: loss partials, round-9 verbatim (res2 bit-identical).
// ---------------------------------------------------------------------------
extern "C" __global__ __launch_bounds__(512)
void k_front(const float* __restrict__ x, const float* __restrict__ nl,
             const float* __restrict__ tgt, const float* __restrict__ W,
             const float* __restrict__ bias, const float* __restrict__ nsamp,
             float* __restrict__ xp, float* __restrict__ res2) {
    __shared__ __align__(16) float ls[4800];      // xsl/nsl/tgl/pt (19.2 KB)
    const int q  = blockIdx.x;
    const int cx = q & 7, b = q >> 3;
    const int t  = threadIdx.x;

    // ---- phase 1: xpred GEMM (no LDS, no barriers) ----
    {
        const int wv   = __builtin_amdgcn_readfirstlane(t >> 6);  // wave 0..7
        const int rh   = wv >> 1;            // row-group: rows rh*8..rh*8+7
        const int dh   = wv & 1;             // d-half within the 256-window
        const int lane = t & 63;
        const int d    = cx * 256 + dh * 128 + 2 * lane;   // even, 8B-aligned
        if (d < ND) {
            float acc[8][2];
            #pragma unroll
            for (int r = 0; r < 8; ++r) { acc[r][0] = 0.f; acc[r][1] = 0.f; }
            const int row0 = b * NG + rh * 8;
            for (int k = 0; k < NK; k += 4) {
                const float2 w0 = *(const float2*)&W[(size_t)(k + 0) * ND + d];
                const float2 w1 = *(const float2*)&W[(size_t)(k + 1) * ND + d];
                const float2 w2 = *(const float2*)&W[(size_t)(k + 2) * ND + d];
                const float2 w3 = *(const float2*)&W[(size_t)(k + 3) * ND + d];
                #pragma unroll
                for (int r = 0; r < 8; ++r) {
                    // wave-uniform addresses -> scalar (SGPR) loads
                    float x0, x1, x2, x3;
                    if (k < NDIN) {
                        const float* xr = &x[(size_t)(row0 + r) * NDIN + k];
                        x0 = xr[0]; x1 = xr[1]; x2 = xr[2]; x3 = xr[3];
                    } else {
                        const float* nr = &nsamp[(size_t)(row0 + r) * NE + (k - NDIN)];
                        x0 = nr[0]; x1 = nr[1]; x2 = nr[2]; x3 = nr[3];
                    }
                    acc[r][0] += x0 * w0.x + x1 * w1.x + x2 * w2.x + x3 * w3.x;
                    acc[r][1] += x0 * w0.y + x1 * w1.y + x2 * w2.y + x3 * w3.y;
                }
            }
            const float2 bv = *(const float2*)&bias[d];
            #pragma unroll
            for (int r = 0; r < 8; ++r) {
                float2 o;
                o.x = softplusf(acc[r][0] + bv.x);
                o.y = softplusf(acc[r][1] + bv.y);
                *(float2*)&xp[(size_t)(row0 + r) * ND + d] = o;
            }
        }
    }

    // ---- phase 2: loss partials (round-9 loss_path verbatim) ----
    float* xsl = ls;                 // 256
    float* nsl = ls + 256;           // 256
    float* tgl = ls + 512;           // 252
    float* pt  = ls + 764;           // 16 x 252

    if (t < 256) {
        const float* xb = x + (size_t)b * NG * NDIN;
        float s = 0.f;
        for (int g = 0; g < NG; ++g) s += xb[g * NDIN + t];
        xsl[t] = s;
        const float* nb = nl + (size_t)b * NG * (NM * NE);
        float s2 = 0.f;
        for (int g = 0; g < NG; ++g) s2 += nb[g * (NM * NE) + t];
        nsl[t] = s2;
    }

    int tm = 0, tn = 0;
    if (t >= 16 && t < 152) {
        int p = t - 16;
        for (int m = 0; m < NM; ++m) {
            int c = NM - m;
            if (p < c) { tm = m; tn = m + p; break; }
            p -= c;
        }
    }
    __syncthreads();

    const int d = cx * 250 + t;
    if (t < 250) {
        tgl[t] = tgt[b * ND + d];
        float xw = 0.f;
        #pragma unroll 8
        for (int k = 0; k < NDIN; ++k) xw += xsl[k] * W[(size_t)k * ND + d];
        float we[NE];
        #pragma unroll
        for (int e = 0; e < NE; ++e) we[e] = W[(size_t)(NDIN + e) * ND + d];
        const float base0 = xw + (float)NG * bias[d];
        #pragma unroll
        for (int m = 0; m < NM; ++m) {
            float pm = base0;
            #pragma unroll
            for (int e = 0; e < NE; ++e) pm += nsl[m * NE + e] * we[e];
            pt[m * 252 + t] = pm;
        }
    }
    if (t < 32) {                      // zero-pad cols 250,251
        pt[(t >> 1) * 252 + 250 + (t & 1)] = 0.f;
        if (t < 2) tgl[250 + t] = 0.f;
    }
    __syncthreads();

    float acc = 0.f;
    if (t < 16) {
        const float4* pa  = (const float4*)&pt[t * 252];
        const float4* tga = (const float4*)&tgl[0];
        for (int i = 0; i < 63; ++i) {
            float4 pv = pa[i], tv = tga[i];
            float e0 = pv.x - tv.x, e1 = pv.y - tv.y, e2 = pv.z - tv.z, e3 = pv.w - tv.w;
            acc += e0 * e0 + e1 * e1 + e2 * e2 + e3 * e3;
        }
    } else if (t < 152) {
        const float4* pa = (const float4*)&pt[tm * 252];
        const float4* pb = (const float4*)&pt[tn * 252];
        for (int i = 0; i < 63; ++i) {
            float4 u = pa[i], v = pb[i];
            acc += u.x * v.x + u.y * v.y + u.z * v.z + u.w * v.w;
        }
    }
    if (t < 152) res2[((size_t)b * 8 + cx) * 152 + t] = acc;
}

// ---------------------------------------------------------------------------
// Kernel B: 65 blocks x 256 threads, __launch_bounds__(256, 1).
//   blocks 0..63 : IPF + integerization, 8 d/thread (y0[8][32] = 256 VGPRs;
//                  cap 512 at 1 wave/EU -> no spill).  4 waves per barrier
//                  (was 8), 1 wave/SIMD, 2x ILP per thread — attacks the
//                  2.9 us/iter vs 0.6 us issue-floor gap of the 512-thr IPF.
//   block  64    : loss combine (writes out[0] directly), hidden under IPF.
// ---------------------------------------------------------------------------
__device__ __forceinline__ void ipf_path(
        const float* __restrict__ xp, const int* __restrict__ tsum,
        float* __restrict__ out, float* smem, int b, int t) {
    const int lane = t & 63, w = t >> 6;      // wave 0..3
    const int d0 = t * 8;
    const bool valid = (d0 < ND);             // t < 250
    const int g_own = (lane >> 1) & 31;

    float* wred = smem;                       // [2][4][32] floats, dbuf

    // load y0 = max(x_pred, 0): 8 d per thread
    float y0r[8][NG];
    #pragma unroll
    for (int g = 0; g < NG; ++g) {
        float4 v0 = make_float4(0.f, 0.f, 0.f, 0.f);
        float4 v1 = make_float4(0.f, 0.f, 0.f, 0.f);
        if (valid) {
            const float* base = xp + (size_t)(b * NG + g) * ND + d0;
            v0 = *(const float4*)(base);
            v1 = *(const float4*)(base + 4);
        }
        y0r[0][g] = fmaxf(v0.x, 0.f); y0r[1][g] = fmaxf(v0.y, 0.f);
        y0r[2][g] = fmaxf(v0.z, 0.f); y0r[3][g] = fmaxf(v0.w, 0.f);
        y0r[4][g] = fmaxf(v1.x, 0.f); y0r[5][g] = fmaxf(v1.y, 0.f);
        y0r[6][g] = fmaxf(v1.z, 0.f); y0r[7][g] = fmaxf(v1.w, 0.f);
    }
    float Cc[8];
    #pragma unroll
    for (int j = 0; j < 8; ++j) Cc[j] = 0.f;
    if (valid) {
        const int4 c0 = *(const int4*)(tsum + (size_t)b * ND + d0);
        const int4 c1 = *(const int4*)(tsum + (size_t)b * ND + d0 + 4);
        Cc[0] = (float)c0.x; Cc[1] = (float)c0.y; Cc[2] = (float)c0.z; Cc[3] = (float)c0.w;
        Cc[4] = (float)c1.x; Cc[5] = (float)c1.y; Cc[6] = (float)c1.z; Cc[7] = (float)c1.w;
    }
    float Ac[8] = {1.f, 1.f, 1.f, 1.f, 1.f, 1.f, 1.f, 1.f};
    float Bown = 1.f;
    float Rown;

    // prologue: row anchors R (buf 0)
    {
        float v[NG];
        #pragma unroll
        for (int g = 0; g < NG; ++g) {
            float s = y0r[0][g];
            #pragma unroll
            for (int j = 1; j < 8; ++j) s += y0r[j][g];
            v[g] = s;
        }
        const float tot = wave_sum32(v, lane);
        if ((lane & 1) == 0) wred[w * NG + g_own] = tot;
        __syncthreads();
        Rown = wred[0 * NG + g_own] + wred[1 * NG + g_own]
             + wred[2 * NG + g_own] + wred[3 * NG + g_own];
    }

    // 60 IPF iterations, ONE barrier each (double-buffered wred)
    for (int q = 1; q <= 60; ++q) {
        float s[8];
        #pragma unroll
        for (int j = 0; j < 8; ++j) s[j] = 0.f;
        #pragma unroll
        for (int g = 0; g < NG; ++g) {
            const float bg = readlane_f(Bown, 2 * g);
            #pragma unroll
            for (int j = 0; j < 8; ++j) s[j] += y0r[j][g] * bg;
        }
        #pragma unroll
        for (int j = 0; j < 8; ++j)
            Ac[j] *= clampf(Cc[j] / fmaxf(Ac[j] * s[j], 1e-12f), 0.75f, 1.25f);
        float v[NG];
        #pragma unroll
        for (int g = 0; g < NG; ++g) {
            float rv = y0r[0][g] * Ac[0];
            #pragma unroll
            for (int j = 1; j < 8; ++j) rv += y0r[j][g] * Ac[j];
            v[g] = rv;
        }
        const float tot = wave_sum32(v, lane);
        const int buf = (q & 1) * (4 * NG);
        if ((lane & 1) == 0) wred[buf + w * NG + g_own] = tot;
        __syncthreads();
        const float rs = wred[buf + 0 * NG + g_own] + wred[buf + 1 * NG + g_own]
                       + wred[buf + 2 * NG + g_own] + wred[buf + 3 * NG + g_own];
        Bown *= clampf(Rown / fmaxf(Bown * rs, 1e-12f), 0.75f, 1.25f);
    }

    // epilogue: two halves of 4 d each (caps register pressure);
    // rank-based neg branch, no dynamic indexing.
    if (!valid) return;

    #pragma unroll
    for (int jh = 0; jh < 2; ++jh) {
        unsigned pk[NG];
        #pragma unroll
        for (int g = 0; g < NG; ++g) pk[g] = 0u;
        #pragma unroll
        for (int jj = 0; jj < 4; ++jj) {
            const int j = jh * 4 + jj;
            float fr[NG];
            int   yv[NG];
            float s = 0.f;
            #pragma unroll
            for (int g = 0; g < NG; ++g) {
                const float z = y0r[j][g] * Ac[j] * readlane_f(Bown, 2 * g);
                fr[g] = z;
                s += z;
            }
            const float F = Cc[j] / fmaxf(s, 1e-12f);
            int isum = 0;
            #pragma unroll
            for (int g = 0; g < NG; ++g) {
                const float y = fr[g] * F;
                const float fl = floorf(y);
                yv[g] = (int)fl;
                fr[g] = y - fl;
                isum += yv[g];
            }
            const int Ci = (int)Cc[j];
            const int need = Ci - isum;
            const int pos = max(need, 0);
            const int q = pos >> 5;
            const int r = pos & 31;
            #pragma unroll
            for (int g = 0; g < NG; ++g) yv[g] += q;
            #pragma unroll
            for (int g = 0; g < NG; ++g) {   // stable DESCENDING rank on frac
                int rank = 0;
                #pragma unroll
                for (int h = 0; h < NG; ++h) {
                    if (h == g) continue;
                    rank += (h < g) ? (fr[h] >= fr[g] ? 1 : 0) : (fr[h] > fr[g] ? 1 : 0);
                }
                if (rank < r) yv[g] += 1;
            }
            int neg = max(-need, 0);
            neg = min(neg, isum);
            if (__builtin_expect(neg > 0, 0)) {
                const int q2 = neg >> 5;
                int removed = 0;
                #pragma unroll
                for (int g = 0; g < NG; ++g) {
                    const int yb = yv[g];
                    const int yn = max(yb - q2, 0);
                    removed += yb - yn;
                    yv[g] = yn;
                }
                const int r2 = neg - removed;
                if (r2 > 0) {
                    const float INF = __builtin_inff();
                    #pragma unroll
                    for (int g = 0; g < NG; ++g) {
                        const float fg = (yv[g] > 0) ? fr[g] : INF;
                        int rank = 0;
                        #pragma unroll
                        for (int h = 0; h < NG; ++h) {
                            if (h == g) continue;
                            const float fh = (yv[h] > 0) ? fr[h] : INF;
                            rank += (h < g) ? (fh <= fg ? 1 : 0) : (fh < fg ? 1 : 0);
                        }
                        if (rank < r2) yv[g] = max(yv[g] - 1, 0);
                    }
                }
            }
            #pragma unroll
            for (int g = 0; g < NG; ++g)
                pk[g] |= ((unsigned)yv[g]) << (8 * jj);   // yv <= C <= 199
        }
        #pragma unroll
        for (int g = 0; g < NG; ++g) {
            float* op = &out[1 + (size_t)(b * NG + g) * ND + d0 + jh * 4];
            op[0] = (float)(pk[g] & 0xffu);
            op[1] = (float)((pk[g] >> 8) & 0xffu);
            op[2] = (float)((pk[g] >> 16) & 0xffu);
            op[3] = (float)((pk[g] >> 24) & 0xffu);
        }
    }
}

__device__ __forceinline__ void combine_path(
        const float* __restrict__ res2, float* __restrict__ out,
        float* ls, int t) {
    for (int idx = t; idx < NB * 152; idx += 256) {
        const int b = idx / 152, tau = idx - b * 152;
        float s = 0.f;
        #pragma unroll
        for (int c = 0; c < 8; ++c) s += res2[((size_t)b * 8 + c) * 152 + tau];
        ls[idx] = s;
    }
    __syncthreads();
    float v = 0.f;
    if (t < NB) {
        const float* res = &ls[t * 152];
        float conf = 0.f;
        for (int m = 0; m < NM; ++m) conf += sqrtf(res[m]);
        conf *= (1.f / NM);
        float pd = 0.f;
        for (int m = 0; m < NM; ++m) {
            const int offm = 16 + m * NM - m * (m - 1) / 2;
            const float sqm = res[offm];
            for (int n = m + 1; n < NM; ++n) {
                const int offn = 16 + n * NM - n * (n - 1) / 2;
                const float sqn = res[offn];
                const float inn = res[offm + (n - m)];
                pd += sqrtf(fmaxf(sqm + sqn - 2.f * inn, 1e-6f));
            }
        }
        pd = 2.f * pd / (float)(NM * (NM - 1));
        v = (conf - 0.5f * pd) * (1.f / NB);
    }
    if (t < 64) {
        #pragma unroll
        for (int o = 32; o >= 1; o >>= 1) v += __shfl_xor(v, o);
        if (t == 0) out[0] = v;
    }
}

extern "C" __global__ __launch_bounds__(256, 1)
void k_back(const float* __restrict__ xp, const int* __restrict__ tsum,
            const float* __restrict__ res2, float* __restrict__ out) {
    __shared__ float smem[NB * 152];   // 38.9 KB (combine); IPF uses 256 floats
    const int bid = blockIdx.x;
    const int t = threadIdx.x;
    if (bid < NB) {
        ipf_path(xp, tsum, out, smem, bid, t);
    } else {
        combine_path(res2, out, smem, t);
    }
}

// ---------------------------------------------------------------------------
extern "C" void kernel_launch(void* const* d_in, const int* in_sizes, int n_in,
                              void* d_out, int out_size, void* d_ws, size_t ws_size,
                              hipStream_t stream) {
    const float* x     = (const float*)d_in[0];
    const float* tgt   = (const float*)d_in[1];
    const int*   tsum  = (const int*)d_in[2];
    const float* W     = (const float*)d_in[3];
    const float* bias  = (const float*)d_in[4];
    const float* nl    = (const float*)d_in[5];
    const float* nsamp = (const float*)d_in[6];
    float* out = (float*)d_out;

    (void)in_sizes; (void)n_in; (void)out_size; (void)ws_size;

    const size_t XPB = (size_t)2048 * 2000 * 4;        // 16,384,000 B
    float* xp   = (float*)d_ws;
    float* res2 = (float*)((char*)d_ws + XPB);         // 64*8*152 floats

    hipLaunchKernelGGL(k_front, dim3(512), dim3(512), 0, stream,
                       x, nl, tgt, W, bias, nsamp, xp, res2);
    hipLaunchKernelGGL(k_back, dim3(NB + 1), dim3(256), 0, stream,
                       xp, tsum, res2, out);
}